// Round 3
// baseline (4563.855 us; speedup 1.0000x reference)
//
#include <hip/hip_runtime.h>
#include <cstddef>
#include <cstdint>

namespace {

constexpr int kB  = 4096;   // batch
constexpr int kIN = 4096;
constexpr int kFS = 4096;
constexpr int kS  = 64;
constexpr int kH  = 512;
constexpr int kNG = 2048;   // 4*H
constexpr int kKC = 576;    // 64 (input slice) + 512 (hidden)
constexpr int kKTiles = kKC / 32;  // 18

typedef __bf16 bf16_t;
typedef __bf16 bfrag  __attribute__((ext_vector_type(8)));
typedef __bf16 bf16v4 __attribute__((ext_vector_type(4)));
typedef float  f32x4  __attribute__((ext_vector_type(4)));

__device__ __forceinline__ void gload16(const void* g, void* l) {
  __builtin_amdgcn_global_load_lds(
      (const __attribute__((address_space(1))) void*)g,
      (__attribute__((address_space(3))) void*)l, 16, 0, 0);
}

__device__ __forceinline__ float sigf(float x) { return 1.0f / (1.0f + __expf(-x)); }
__device__ __forceinline__ float tanh_fast(float x) {
  float e = __expf(2.0f * x);
  return 1.0f - 2.0f / (e + 1.0f);
}

// ---------------- pack kernels ----------------

__global__ __launch_bounds__(256) void f2b4_kernel(const float* __restrict__ in,
                                                   bf16_t* __restrict__ out, int n4) {
  int i = blockIdx.x * 256 + threadIdx.x;
  if (i >= n4) return;
  float4 v = reinterpret_cast<const float4*>(in)[i];
  bf16v4 o = {(bf16_t)v.x, (bf16_t)v.y, (bf16_t)v.z, (bf16_t)v.w};
  *reinterpret_cast<bf16v4*>(out + (size_t)i * 4) = o;
}

__global__ __launch_bounds__(256) void pack_wcat_kernel(
    const float* __restrict__ Wih_l, const float* __restrict__ Whh_l,
    const float* __restrict__ Wih_r, const float* __restrict__ Whh_r,
    const float* __restrict__ Wih_d, const float* __restrict__ Whh_d,
    bf16_t* __restrict__ wcat) {
  int idx = blockIdx.x * 256 + threadIdx.x;
  if (idx >= 3 * kNG * kKC) return;
  int m = idx / (kNG * kKC);
  int rem = idx - m * (kNG * kKC);
  int rr = rem / kKC;
  int k  = rem - rr * kKC;
  int u = rr >> 2, g = rr & 3;
  int orow = g * kH + u;
  const float* Wih = (m == 0) ? Wih_l : (m == 1) ? Wih_r : Wih_d;
  const float* Whh = (m == 0) ? Whh_l : (m == 1) ? Whh_r : Whh_d;
  float v = (k < 64) ? Wih[(size_t)orow * 64 + k] : Whh[(size_t)orow * 512 + (k - 64)];
  wcat[idx] = (bf16_t)v;
}

__global__ __launch_bounds__(256) void pack_bias_kernel(
    const float* __restrict__ bih_l, const float* __restrict__ bhh_l,
    const float* __restrict__ bih_r, const float* __restrict__ bhh_r,
    const float* __restrict__ bih_d, const float* __restrict__ bhh_d,
    float* __restrict__ biasc) {
  int idx = blockIdx.x * 256 + threadIdx.x;
  if (idx >= 3 * kNG) return;
  int m = idx / kNG;
  int rr = idx - m * kNG;
  int u = rr >> 2, g = rr & 3;
  int orow = g * kH + u;
  const float* bi = (m == 0) ? bih_l : (m == 1) ? bih_r : bih_d;
  const float* bh = (m == 0) ? bhh_l : (m == 1) ? bhh_r : bhh_d;
  biasc[idx] = bi[orow] + bh[orow];
}

__global__ __launch_bounds__(256) void pack_hc_kernel(const float* __restrict__ h0,
                                                      const float* __restrict__ c0,
                                                      bf16_t* __restrict__ hbuf0,
                                                      float* __restrict__ cbuf, int n) {
  int i = blockIdx.x * 256 + threadIdx.x;
  if (i >= n) return;
  hbuf0[i] = (bf16_t)h0[i];
  cbuf[i]  = c0[i];
}

__global__ __launch_bounds__(256) void transpose64_kernel(const bf16_t* __restrict__ feat,
                                                          bf16_t* __restrict__ featT) {
  __shared__ bf16_t tile[64][65];
  const int b = blockIdx.x;
  const bf16_t* src = feat + (size_t)b * kFS;
  bf16_t* dst = featT + (size_t)b * kFS;
  for (int i = threadIdx.x; i < 4096; i += 256) tile[i >> 6][i & 63] = src[i];
  __syncthreads();
  for (int i = threadIdx.x; i < 4096; i += 256) dst[i] = tile[i & 63][i >> 6];
}

// ---------------- feat GEMM (unchanged this round) ----------------

__global__ __launch_bounds__(256, 4) void gemm_feat_kernel(
    const bf16_t* __restrict__ X, const bf16_t* __restrict__ W,
    const float* __restrict__ b1, bf16_t* __restrict__ feat) {
  __shared__ bf16_t As[128 * 32];
  __shared__ bf16_t Bs[128 * 32];
  const int t = threadIdx.x;
  const int bid = blockIdx.x;
  const int widx = (bid & 7) * 128 + (bid >> 3);
  const int bm = widx & 31, bn = widx >> 5;
  const int w = t >> 6, l = t & 63;
  const int wm = (w >> 1) * 64, wn = (w & 1) * 64;
  const int sr = t >> 2, sk = (t & 3) * 8;
  const int lr = l & 15, lk = (l >> 4) * 8;
  const int lrow4 = (l >> 4) * 4;

  f32x4 acc[4][4];
#pragma unroll
  for (int i = 0; i < 4; ++i)
#pragma unroll
    for (int j = 0; j < 4; ++j) acc[i][j] = (f32x4){0.f, 0.f, 0.f, 0.f};

  const bf16_t* ga = X + (size_t)(bm * 128 + sr) * kIN + sk;
  const bf16_t* gb = W + (size_t)(bn * 128 + sr) * kIN + sk;
  bf16_t* lA = As + w * 512;
  bf16_t* lB = Bs + w * 512;

  for (int kt = 0; kt < kIN / 32; ++kt) {
    gload16(ga, lA);
    gload16(ga + (size_t)64 * kIN, lA + 2048);
    gload16(gb, lB);
    gload16(gb + (size_t)64 * kIN, lB + 2048);
    ga += 32; gb += 32;
    __syncthreads();
    bfrag a[4], b[4];
#pragma unroll
    for (int mi = 0; mi < 4; ++mi)
      a[mi] = *reinterpret_cast<const bfrag*>(&As[(wm + mi * 16 + lr) * 32 + lk]);
#pragma unroll
    for (int ni = 0; ni < 4; ++ni)
      b[ni] = *reinterpret_cast<const bfrag*>(&Bs[(wn + ni * 16 + lr) * 32 + lk]);
#pragma unroll
    for (int mi = 0; mi < 4; ++mi)
#pragma unroll
      for (int ni = 0; ni < 4; ++ni)
        acc[mi][ni] = __builtin_amdgcn_mfma_f32_16x16x32_bf16(a[mi], b[ni], acc[mi][ni], 0, 0, 0);
    __syncthreads();
  }

#pragma unroll
  for (int ni = 0; ni < 4; ++ni) {
    const int col = bn * 128 + wn + ni * 16 + lr;
    const float bb = b1[col];
#pragma unroll
    for (int mi = 0; mi < 4; ++mi) {
#pragma unroll
      for (int r = 0; r < 4; ++r) {
        const int row = bm * 128 + wm + mi * 16 + lrow4 + r;
        float v = acc[mi][ni][r] + bb;
        feat[(size_t)row * kFS + col] = (bf16_t)fmaxf(v, 0.0f);
      }
    }
  }
}

// ---------------- fused LSTM step, pipelined ----------------
// 256x128 tile, 4 waves (wave-tile 128x64), BK=32, triple-buffered LDS (3x24KB),
// lookahead-2 staging via global_load_lds, counted vmcnt(6) (never 0 in loop),
// raw s_barrier (no vmcnt drain), T2 XOR slot-swizzle, setprio around MFMA.
// LDS buffer b at smem + b*24576: A[256][32] (16KB) then B[128][32] (8KB).
// Swizzle: LDS slot (row, s) holds global slot s ^ ((row>>1)&3); staging keeps the
// LDS dest LINEAR and pre-swizzles the GLOBAL source column (rule #21); ds_read
// applies the same XOR. Kills the 8-way bank conflict of stride-64B row reads.

__global__ __launch_bounds__(256, 2) void lstm_step_kernel(
    const bf16_t* __restrict__ feat, const bf16_t* __restrict__ featT,
    const bf16_t* __restrict__ wcat, const float* __restrict__ biasc,
    const bf16_t* __restrict__ hin, bf16_t* __restrict__ hout,
    float* __restrict__ cbuf, int s) {
  __shared__ __align__(16) unsigned char smem[3 * 24576];  // 72 KB -> 2 blocks/CU

  const int t = threadIdx.x;
  const int bid = blockIdx.x;                 // grid 1024 = 16 bm x 16 bn x 4 cell
  const int widx = (bid & 7) * 128 + (bid >> 3);  // XCD swizzle (bijective, 1024%8==0)
  const int cell = widx >> 8;
  const int rwk  = widx & 255;
  const int bm = rwk >> 4, bn = rwk & 15;
  const int w = t >> 6, l = t & 63;
  const int wm = (w >> 1) * 128, wn = (w & 1) * 64;
  const int sr = t >> 2;                      // staging row within 64-row chunk
  const int skS = ((t & 3) ^ ((t >> 3) & 3)) * 8;      // pre-swizzled global col (elems)
  const int lr = l & 15;
  const int lkS = (((l >> 4) ^ ((l >> 1) & 3)) * 8);   // swizzled ds_read col (elems)
  const int lrow4 = (l >> 4) * 4;

  const bf16_t* xsrc = (cell < 2) ? feat : featT;
  const int off = ((cell & 1) ? (63 - s) : s) * 64;
  const int mat = (cell < 2) ? cell : 2;
  const bf16_t* Wm = wcat + (size_t)mat * kNG * kKC;
  const bf16_t* hc = hin + (size_t)cell * kB * kH;

  const bf16_t* gax2 = xsrc + (size_t)(bm * 256 + sr) * kFS + off + skS;
  const bf16_t* gah2 = hc + (size_t)(bm * 256 + sr) * kH + skS;
  const bf16_t* gbt  = Wm + (size_t)(bn * 128 + sr) * kKC + skS;

  // phase-1 stage: A rows [0,128) (2 loads) + B rows [0,64) (1 load)
  auto stageP1 = [&](int kt, int b) {
    char* base = (char*)smem + b * 24576;
    bf16_t* dA = (bf16_t*)base + w * 512;
    bf16_t* dB = (bf16_t*)(base + 16384) + w * 512;
    if (kt < 2) {
      const bf16_t* g = gax2 + kt * 32;
      gload16(g, dA);
      gload16(g + (size_t)64 * kFS, dA + 2048);
    } else {
      const bf16_t* g = gah2 + (kt - 2) * 32;
      gload16(g, dA);
      gload16(g + (size_t)64 * kH, dA + 2048);
    }
    gload16(gbt + kt * 32, dB);
  };
  // phase-2 stage: A rows [128,256) (2 loads) + B rows [64,128) (1 load)
  auto stageP2 = [&](int kt, int b) {
    char* base = (char*)smem + b * 24576;
    bf16_t* dA = (bf16_t*)base + 4096 + w * 512;
    bf16_t* dB = (bf16_t*)(base + 16384) + 2048 + w * 512;
    if (kt < 2) {
      const bf16_t* g = gax2 + kt * 32 + (size_t)128 * kFS;
      gload16(g, dA);
      gload16(g + (size_t)64 * kFS, dA + 2048);
    } else {
      const bf16_t* g = gah2 + (kt - 2) * 32 + (size_t)128 * kH;
      gload16(g, dA);
      gload16(g + (size_t)64 * kH, dA + 2048);
    }
    gload16(gbt + kt * 32 + (size_t)64 * kKC, dB);
  };

  f32x4 acc[8][4];
#pragma unroll
  for (int i = 0; i < 8; ++i)
#pragma unroll
    for (int j = 0; j < 4; ++j) acc[i][j] = (f32x4){0.f, 0.f, 0.f, 0.f};

  // prologue: stage tiles 0,1 (6 loads each); wait tile0 (leave tile1's 6 in flight)
  stageP1(0, 0); stageP2(0, 0);
  stageP1(1, 1); stageP2(1, 1);
  asm volatile("s_waitcnt vmcnt(6)" ::: "memory");
  __builtin_amdgcn_sched_barrier(0);
  __builtin_amdgcn_s_barrier();

  for (int kt = 0; kt < kKTiles; ++kt) {
    const int cur = kt % 3;
    const bf16_t* Asb = (const bf16_t*)(smem + cur * 24576);
    const bf16_t* Bsb = (const bf16_t*)(smem + cur * 24576 + 16384);
    const bool pf = (kt + 2 < kKTiles);
    const int nb = (kt + 2) % 3;   // == (kt-1)%3: holds dead tile kt-1

    // ---- phase 1: stage half of tile kt+2; compute mi=0..3 ----
    if (pf) stageP1(kt + 2, nb);
    bfrag af[8], bf[4];
#pragma unroll
    for (int mi = 0; mi < 4; ++mi)
      af[mi] = *reinterpret_cast<const bfrag*>(&Asb[(wm + mi * 16 + lr) * 32 + lkS]);
#pragma unroll
    for (int ni = 0; ni < 4; ++ni)
      bf[ni] = *reinterpret_cast<const bfrag*>(&Bsb[(wn + ni * 16 + lr) * 32 + lkS]);
    __builtin_amdgcn_s_setprio(1);
#pragma unroll
    for (int mi = 0; mi < 4; ++mi)
#pragma unroll
      for (int ni = 0; ni < 4; ++ni)
        acc[mi][ni] = __builtin_amdgcn_mfma_f32_16x16x32_bf16(af[mi], bf[ni], acc[mi][ni], 0, 0, 0);
    __builtin_amdgcn_s_setprio(0);
    __builtin_amdgcn_s_barrier();

    // ---- phase 2: stage other half of tile kt+2; compute mi=4..7 ----
    if (pf) stageP2(kt + 2, nb);
#pragma unroll
    for (int mi = 4; mi < 8; ++mi)
      af[mi] = *reinterpret_cast<const bfrag*>(&Asb[(wm + mi * 16 + lr) * 32 + lkS]);
    __builtin_amdgcn_s_setprio(1);
#pragma unroll
    for (int mi = 4; mi < 8; ++mi)
#pragma unroll
      for (int ni = 0; ni < 4; ++ni)
        acc[mi][ni] = __builtin_amdgcn_mfma_f32_16x16x32_bf16(af[mi], bf[ni], acc[mi][ni], 0, 0, 0);
    __builtin_amdgcn_s_setprio(0);

    // end-of-iter: ensure tile kt+1 fully landed before any wave reads it.
    if (kt < kKTiles - 2) {
      asm volatile("s_waitcnt vmcnt(6)" ::: "memory");   // leave tile kt+2's 6 in flight
    } else if (kt == kKTiles - 2) {
      asm volatile("s_waitcnt vmcnt(0)" ::: "memory");   // tail drain (last tile)
    }
    __builtin_amdgcn_sched_barrier(0);
    __builtin_amdgcn_s_barrier();
  }

  // ---- epilogue: 4 passes of 64 rows; Gs[64][132] aliases smem (all reads done) ----
  float* Gs = (float*)smem;
  const float* biasn = biasc + mat * kNG + bn * 128;
#pragma unroll
  for (int pass = 0; pass < 4; ++pass) {
    const int mlo = (pass & 1) * 4;
    if ((w >> 1) == (pass >> 1)) {
#pragma unroll
      for (int ni = 0; ni < 4; ++ni) {
        const int colL = wn + ni * 16 + lr;
        const float bb = biasn[colL];
#pragma unroll
        for (int mi = mlo; mi < mlo + 4; ++mi)
#pragma unroll
          for (int r = 0; r < 4; ++r)
            Gs[((mi - mlo) * 16 + lrow4 + r) * 132 + colL] = acc[mi][ni][r] + bb;
      }
    }
    __syncthreads();
#pragma unroll
    for (int it = 0; it < 8; ++it) {
      const int ci = it * 256 + t;          // 64 rows x 32 units
      const int rowL = ci >> 5;
      const int u = ci & 31;
      const float4 g4 = *reinterpret_cast<const float4*>(&Gs[rowL * 132 + u * 4]);
      const float iv = sigf(g4.x);
      const float fv = sigf(g4.y);
      const float gv = tanh_fast(g4.z);
      const float ov = sigf(g4.w);
      const int batch = bm * 256 + pass * 64 + rowL;
      const int unit = bn * 32 + u;
      const size_t cidx = ((size_t)cell * kB + batch) * kH + unit;
      const float cn = fv * cbuf[cidx] + iv * gv;
      cbuf[cidx] = cn;
      hout[cidx] = (bf16_t)(ov * tanh_fast(cn));
    }
    __syncthreads();
  }
}

// ---------------- head ----------------

__global__ __launch_bounds__(256) void head_kernel(const bf16_t* __restrict__ hfin,
                                                   const float* __restrict__ W3,
                                                   const float* __restrict__ b3,
                                                   float* __restrict__ out) {
  const int b = blockIdx.x, t = threadIdx.x;
  float acc[10];
#pragma unroll
  for (int j = 0; j < 10; ++j) acc[j] = 0.f;
  for (int k = t; k < 2048; k += 256) {
    const int cell = k >> 9, u = k & 511;
    const float hv = (float)hfin[((size_t)cell * kB + b) * kH + u];
#pragma unroll
    for (int j = 0; j < 10; ++j) acc[j] += hv * W3[j * 2048 + k];
  }
  __shared__ float red[256];
  __shared__ float logits[10];
  for (int j = 0; j < 10; ++j) {
    red[t] = acc[j];
    __syncthreads();
    for (int o2 = 128; o2 > 0; o2 >>= 1) {
      if (t < o2) red[t] += red[t + o2];
      __syncthreads();
    }
    if (t == 0) logits[j] = red[0] + b3[j];
    __syncthreads();
  }
  if (t == 0) {
    float mx = logits[0];
    for (int j = 1; j < 10; ++j) mx = fmaxf(mx, logits[j]);
    float se = 0.f;
    for (int j = 0; j < 10; ++j) se += expf(logits[j] - mx);
    const float lse = mx + logf(se);
    for (int j = 0; j < 10; ++j) out[(size_t)b * 10 + j] = logits[j] - lse;
  }
}

}  // namespace

extern "C" void kernel_launch(void* const* d_in, const int* in_sizes, int n_in,
                              void* d_out, int out_size, void* d_ws, size_t ws_size,
                              hipStream_t stream) {
  const float* x     = (const float*)d_in[0];
  const float* h0    = (const float*)d_in[1];
  const float* c0    = (const float*)d_in[2];
  const float* W1    = (const float*)d_in[3];
  const float* b1    = (const float*)d_in[4];
  const float* Wih_l = (const float*)d_in[5];
  const float* Whh_l = (const float*)d_in[6];
  const float* bih_l = (const float*)d_in[7];
  const float* bhh_l = (const float*)d_in[8];
  const float* Wih_r = (const float*)d_in[9];
  const float* Whh_r = (const float*)d_in[10];
  const float* bih_r = (const float*)d_in[11];
  const float* bhh_r = (const float*)d_in[12];
  const float* Wih_d = (const float*)d_in[13];
  const float* Whh_d = (const float*)d_in[14];
  const float* bih_d = (const float*)d_in[15];
  const float* bhh_d = (const float*)d_in[16];
  const float* W3    = (const float*)d_in[17];
  const float* b3    = (const float*)d_in[18];
  float* out = (float*)d_out;

  char* p = (char*)d_ws;
  auto take = [&](size_t bytes) {
    char* r = p;
    p += (bytes + 255) & ~(size_t)255;
    return r;
  };
  bf16_t* xb    = (bf16_t*)take((size_t)kB * kIN * 2);   // later reused as featT
  bf16_t* w1b   = (bf16_t*)take((size_t)kFS * kIN * 2);  // later reused as hbuf (2 slots)
  bf16_t* feat  = (bf16_t*)take((size_t)kB * kFS * 2);
  bf16_t* wcat  = (bf16_t*)take((size_t)3 * kNG * kKC * 2);
  float*  biasc = (float*)take((size_t)3 * kNG * 4);
  float*  cbuf  = (float*)take((size_t)4 * kB * kH * 4);
  bf16_t* featT = xb;   // safe: gemm_feat (reads xb) precedes transpose (writes featT)
  bf16_t* hbuf  = w1b;  // safe: gemm_feat (reads w1b) precedes pack_hc
  const size_t HSZ = (size_t)4 * kB * kH;

  f2b4_kernel<<<(kB * kIN / 4) / 256, 256, 0, stream>>>(x, xb, kB * kIN / 4);
  f2b4_kernel<<<(kFS * kIN / 4) / 256, 256, 0, stream>>>(W1, w1b, kFS * kIN / 4);
  gemm_feat_kernel<<<dim3(1024), 256, 0, stream>>>(xb, w1b, b1, feat);
  transpose64_kernel<<<kB, 256, 0, stream>>>(feat, featT);
  pack_wcat_kernel<<<(3 * kNG * kKC + 255) / 256, 256, 0, stream>>>(
      Wih_l, Whh_l, Wih_r, Whh_r, Wih_d, Whh_d, wcat);
  pack_bias_kernel<<<(3 * kNG + 255) / 256, 256, 0, stream>>>(
      bih_l, bhh_l, bih_r, bhh_r, bih_d, bhh_d, biasc);
  pack_hc_kernel<<<(int)(HSZ / 256), 256, 0, stream>>>(h0, c0, hbuf, cbuf, (int)HSZ);

  for (int s = 0; s < 64; ++s) {
    lstm_step_kernel<<<dim3(1024), 256, 0, stream>>>(
        feat, featT, wcat, biasc,
        hbuf + (size_t)(s & 1) * HSZ, hbuf + (size_t)((s + 1) & 1) * HSZ, cbuf, s);
  }
  head_kernel<<<kB, 256, 0, stream>>>(hbuf, W3, b3, out);
}

// Round 4
// 4383.281 us; speedup vs baseline: 1.0412x; 1.0412x over previous
//
#include <hip/hip_runtime.h>
#include <cstddef>
#include <cstdint>

namespace {

constexpr int kB  = 4096;   // batch
constexpr int kIN = 4096;
constexpr int kFS = 4096;
constexpr int kS  = 64;
constexpr int kH  = 512;
constexpr int kNG = 2048;   // 4*H
constexpr int kKC = 576;    // 64 (input slice) + 512 (hidden)
constexpr int kKTiles = kKC / 32;  // 18

typedef __bf16 bf16_t;
typedef __bf16 bfrag  __attribute__((ext_vector_type(8)));
typedef __bf16 bf16v4 __attribute__((ext_vector_type(4)));
typedef float  f32x4  __attribute__((ext_vector_type(4)));

__device__ __forceinline__ void gload16(const void* g, void* l) {
  __builtin_amdgcn_global_load_lds(
      (const __attribute__((address_space(1))) void*)g,
      (__attribute__((address_space(3))) void*)l, 16, 0, 0);
}

__device__ __forceinline__ float sigf(float x) { return 1.0f / (1.0f + __expf(-x)); }
__device__ __forceinline__ float tanh_fast(float x) {
  float e = __expf(2.0f * x);
  return 1.0f - 2.0f / (e + 1.0f);
}

// ---------------- pack kernels ----------------

__global__ __launch_bounds__(256) void f2b4_kernel(const float* __restrict__ in,
                                                   bf16_t* __restrict__ out, int n4) {
  int i = blockIdx.x * 256 + threadIdx.x;
  if (i >= n4) return;
  float4 v = reinterpret_cast<const float4*>(in)[i];
  bf16v4 o = {(bf16_t)v.x, (bf16_t)v.y, (bf16_t)v.z, (bf16_t)v.w};
  *reinterpret_cast<bf16v4*>(out + (size_t)i * 4) = o;
}

__global__ __launch_bounds__(256) void pack_wcat_kernel(
    const float* __restrict__ Wih_l, const float* __restrict__ Whh_l,
    const float* __restrict__ Wih_r, const float* __restrict__ Whh_r,
    const float* __restrict__ Wih_d, const float* __restrict__ Whh_d,
    bf16_t* __restrict__ wcat) {
  int idx = blockIdx.x * 256 + threadIdx.x;
  if (idx >= 3 * kNG * kKC) return;
  int m = idx / (kNG * kKC);
  int rem = idx - m * (kNG * kKC);
  int rr = rem / kKC;
  int k  = rem - rr * kKC;
  int u = rr >> 2, g = rr & 3;
  int orow = g * kH + u;
  const float* Wih = (m == 0) ? Wih_l : (m == 1) ? Wih_r : Wih_d;
  const float* Whh = (m == 0) ? Whh_l : (m == 1) ? Whh_r : Whh_d;
  float v = (k < 64) ? Wih[(size_t)orow * 64 + k] : Whh[(size_t)orow * 512 + (k - 64)];
  wcat[idx] = (bf16_t)v;
}

__global__ __launch_bounds__(256) void pack_bias_kernel(
    const float* __restrict__ bih_l, const float* __restrict__ bhh_l,
    const float* __restrict__ bih_r, const float* __restrict__ bhh_r,
    const float* __restrict__ bih_d, const float* __restrict__ bhh_d,
    float* __restrict__ biasc) {
  int idx = blockIdx.x * 256 + threadIdx.x;
  if (idx >= 3 * kNG) return;
  int m = idx / kNG;
  int rr = idx - m * kNG;
  int u = rr >> 2, g = rr & 3;
  int orow = g * kH + u;
  const float* bi = (m == 0) ? bih_l : (m == 1) ? bih_r : bih_d;
  const float* bh = (m == 0) ? bhh_l : (m == 1) ? bhh_r : bhh_d;
  biasc[idx] = bi[orow] + bh[orow];
}

__global__ __launch_bounds__(256) void pack_hc_kernel(const float* __restrict__ h0,
                                                      const float* __restrict__ c0,
                                                      bf16_t* __restrict__ hbuf0,
                                                      float* __restrict__ cbuf, int n) {
  int i = blockIdx.x * 256 + threadIdx.x;
  if (i >= n) return;
  hbuf0[i] = (bf16_t)h0[i];
  cbuf[i]  = c0[i];
}

__global__ __launch_bounds__(256) void transpose64_kernel(const bf16_t* __restrict__ feat,
                                                          bf16_t* __restrict__ featT) {
  __shared__ bf16_t tile[64][65];
  const int b = blockIdx.x;
  const bf16_t* src = feat + (size_t)b * kFS;
  bf16_t* dst = featT + (size_t)b * kFS;
  for (int i = threadIdx.x; i < 4096; i += 256) tile[i >> 6][i & 63] = src[i];
  __syncthreads();
  for (int i = threadIdx.x; i < 4096; i += 256) dst[i] = tile[i & 63][i >> 6];
}

// ---------------- feat GEMM: feat = relu(x @ W1^T + b1) ----------------
// T2 swizzle: LDS slot (row, s) holds global 16B-slot s ^ ((row>>1)&3).
// Staging keeps LDS dest linear, pre-swizzles the GLOBAL source slot; ds_read
// applies the same XOR. 8-way quarter-wave bank conflict -> 2-way (free).

__global__ __launch_bounds__(256, 4) void gemm_feat_kernel(
    const bf16_t* __restrict__ X, const bf16_t* __restrict__ W,
    const float* __restrict__ b1, bf16_t* __restrict__ feat) {
  __shared__ bf16_t As[128 * 32];
  __shared__ bf16_t Bs[128 * 32];
  const int t = threadIdx.x;
  const int bid = blockIdx.x;
  const int widx = (bid & 7) * 128 + (bid >> 3);
  const int bm = widx & 31, bn = widx >> 5;
  const int w = t >> 6, l = t & 63;
  const int wm = (w >> 1) * 64, wn = (w & 1) * 64;
  const int sr = t >> 2;
  const int skS = ((t & 3) ^ ((t >> 3) & 3)) * 8;      // pre-swizzled global slot
  const int lr = l & 15;
  const int lkS = ((l >> 4) ^ ((l >> 1) & 3)) * 8;     // swizzled ds_read slot
  const int lrow4 = (l >> 4) * 4;

  f32x4 acc[4][4];
#pragma unroll
  for (int i = 0; i < 4; ++i)
#pragma unroll
    for (int j = 0; j < 4; ++j) acc[i][j] = (f32x4){0.f, 0.f, 0.f, 0.f};

  const bf16_t* ga = X + (size_t)(bm * 128 + sr) * kIN + skS;
  const bf16_t* gb = W + (size_t)(bn * 128 + sr) * kIN + skS;
  bf16_t* lA = As + w * 512;
  bf16_t* lB = Bs + w * 512;

  for (int kt = 0; kt < kIN / 32; ++kt) {
    gload16(ga, lA);
    gload16(ga + (size_t)64 * kIN, lA + 2048);
    gload16(gb, lB);
    gload16(gb + (size_t)64 * kIN, lB + 2048);
    ga += 32; gb += 32;
    __syncthreads();
    bfrag a[4], b[4];
#pragma unroll
    for (int mi = 0; mi < 4; ++mi)
      a[mi] = *reinterpret_cast<const bfrag*>(&As[(wm + mi * 16 + lr) * 32 + lkS]);
#pragma unroll
    for (int ni = 0; ni < 4; ++ni)
      b[ni] = *reinterpret_cast<const bfrag*>(&Bs[(wn + ni * 16 + lr) * 32 + lkS]);
#pragma unroll
    for (int mi = 0; mi < 4; ++mi)
#pragma unroll
      for (int ni = 0; ni < 4; ++ni)
        acc[mi][ni] = __builtin_amdgcn_mfma_f32_16x16x32_bf16(a[mi], b[ni], acc[mi][ni], 0, 0, 0);
    __syncthreads();
  }

#pragma unroll
  for (int ni = 0; ni < 4; ++ni) {
    const int col = bn * 128 + wn + ni * 16 + lr;
    const float bb = b1[col];
#pragma unroll
    for (int mi = 0; mi < 4; ++mi) {
#pragma unroll
      for (int r = 0; r < 4; ++r) {
        const int row = bm * 128 + wm + mi * 16 + lrow4 + r;
        float v = acc[mi][ni][r] + bb;
        feat[(size_t)row * kFS + col] = (bf16_t)fmaxf(v, 0.0f);
      }
    }
  }
}

// ---------------- fused LSTM step (R2 structure + T2 swizzle) ----------------
// 128x128 tile, 4 waves, BK=32, single-buffered LDS (16.9 KB -> 4 blocks/CU),
// plain __syncthreads() loop. Gs (32x132 fp32) aliases As/Bs post-loop.

__global__ __launch_bounds__(256, 4) void lstm_step_kernel(
    const bf16_t* __restrict__ feat, const bf16_t* __restrict__ featT,
    const bf16_t* __restrict__ wcat, const float* __restrict__ biasc,
    const bf16_t* __restrict__ hin, bf16_t* __restrict__ hout,
    float* __restrict__ cbuf, int s) {
  __shared__ __align__(16) unsigned char smem[32 * 132 * 4];  // 16896 B
  bf16_t* As = (bf16_t*)smem;            // 128 rows x 32
  bf16_t* Bs = (bf16_t*)(smem + 8192);   // 128 rows x 32
  float*  Gs = (float*)smem;             // 32 rows x 132 (post K-loop)

  const int t = threadIdx.x;
  const int bid = blockIdx.x;
  const int widx = (bid & 7) * 256 + (bid >> 3);   // XCD swizzle, grid 2048
  const int cell = widx >> 9;
  const int rwk  = widx & 511;
  const int bm = rwk >> 4, bn = rwk & 15;
  const int w = t >> 6, l = t & 63;
  const int wm = (w >> 1) * 64, wn = (w & 1) * 64;
  const int sr = t >> 2;
  const int skS = ((t & 3) ^ ((t >> 3) & 3)) * 8;      // pre-swizzled global slot
  const int lr = l & 15;
  const int lkS = ((l >> 4) ^ ((l >> 1) & 3)) * 8;     // swizzled ds_read slot
  const int lrow4 = (l >> 4) * 4;

  const bf16_t* xsrc = (cell < 2) ? feat : featT;
  const int off = ((cell & 1) ? (63 - s) : s) * 64;
  const int mat = (cell < 2) ? cell : 2;
  const bf16_t* Wm = wcat + (size_t)mat * kNG * kKC;
  const bf16_t* hc = hin + (size_t)cell * kB * kH;

  f32x4 acc[4][4];
#pragma unroll
  for (int i = 0; i < 4; ++i)
#pragma unroll
    for (int j = 0; j < 4; ++j) acc[i][j] = (f32x4){0.f, 0.f, 0.f, 0.f};

  const bf16_t* gax = xsrc + (size_t)(bm * 128 + sr) * kFS + off + skS;
  const bf16_t* gah = hc + (size_t)(bm * 128 + sr) * kH + skS;
  const bf16_t* gb  = Wm + (size_t)(bn * 128 + sr) * kKC + skS;
  bf16_t* lA = As + w * 512;
  bf16_t* lB = Bs + w * 512;

  for (int kt = 0; kt < kKTiles; ++kt) {
    if (kt < 2) {  // input-slice part of K
      const bf16_t* ga = gax + kt * 32;
      gload16(ga, lA);
      gload16(ga + (size_t)64 * kFS, lA + 2048);
    } else {       // hidden part of K
      const bf16_t* ga = gah + (kt - 2) * 32;
      gload16(ga, lA);
      gload16(ga + (size_t)64 * kH, lA + 2048);
    }
    gload16(gb, lB);
    gload16(gb + (size_t)64 * kKC, lB + 2048);
    gb += 32;
    __syncthreads();
    bfrag a[4], b[4];
#pragma unroll
    for (int mi = 0; mi < 4; ++mi)
      a[mi] = *reinterpret_cast<const bfrag*>(&As[(wm + mi * 16 + lr) * 32 + lkS]);
#pragma unroll
    for (int ni = 0; ni < 4; ++ni)
      b[ni] = *reinterpret_cast<const bfrag*>(&Bs[(wn + ni * 16 + lr) * 32 + lkS]);
#pragma unroll
    for (int mi = 0; mi < 4; ++mi)
#pragma unroll
      for (int ni = 0; ni < 4; ++ni)
        acc[mi][ni] = __builtin_amdgcn_mfma_f32_16x16x32_bf16(a[mi], b[ni], acc[mi][ni], 0, 0, 0);
    __syncthreads();
  }

  // Epilogue: 4 quarter passes; Gs aliases the dead As/Bs memory.
  const float* biasn = biasc + mat * kNG + bn * 128;
#pragma unroll
  for (int pass = 0; pass < 4; ++pass) {
    const int half = pass >> 1;
    const int mlo  = (pass & 1) * 2;
    if ((w >> 1) == half) {
#pragma unroll
      for (int ni = 0; ni < 4; ++ni) {
        const int colL = wn + ni * 16 + lr;
        const float bb = biasn[colL];
#pragma unroll
        for (int mi = mlo; mi < mlo + 2; ++mi)
#pragma unroll
          for (int r = 0; r < 4; ++r)
            Gs[((mi - mlo) * 16 + lrow4 + r) * 132 + colL] = acc[mi][ni][r] + bb;
      }
    }
    __syncthreads();
#pragma unroll
    for (int it = 0; it < 4; ++it) {
      const int ci = it * 256 + t;          // 32 rows x 32 units
      const int rowL = ci >> 5;
      const int u = ci & 31;
      const float4 g4 = *reinterpret_cast<const float4*>(&Gs[rowL * 132 + u * 4]);
      const float iv = sigf(g4.x);
      const float fv = sigf(g4.y);
      const float gv = tanh_fast(g4.z);
      const float ov = sigf(g4.w);
      const int batch = bm * 128 + half * 64 + mlo * 16 + rowL;
      const int unit = bn * 32 + u;
      const size_t cidx = ((size_t)cell * kB + batch) * kH + unit;
      const float cn = fv * cbuf[cidx] + iv * gv;
      cbuf[cidx] = cn;
      hout[cidx] = (bf16_t)(ov * tanh_fast(cn));
    }
    __syncthreads();
  }
}

// ---------------- head ----------------

__global__ __launch_bounds__(256) void head_kernel(const bf16_t* __restrict__ hfin,
                                                   const float* __restrict__ W3,
                                                   const float* __restrict__ b3,
                                                   float* __restrict__ out) {
  const int b = blockIdx.x, t = threadIdx.x;
  float acc[10];
#pragma unroll
  for (int j = 0; j < 10; ++j) acc[j] = 0.f;
  for (int k = t; k < 2048; k += 256) {
    const int cell = k >> 9, u = k & 511;
    const float hv = (float)hfin[((size_t)cell * kB + b) * kH + u];
#pragma unroll
    for (int j = 0; j < 10; ++j) acc[j] += hv * W3[j * 2048 + k];
  }
  __shared__ float red[256];
  __shared__ float logits[10];
  for (int j = 0; j < 10; ++j) {
    red[t] = acc[j];
    __syncthreads();
    for (int o2 = 128; o2 > 0; o2 >>= 1) {
      if (t < o2) red[t] += red[t + o2];
      __syncthreads();
    }
    if (t == 0) logits[j] = red[0] + b3[j];
    __syncthreads();
  }
  if (t == 0) {
    float mx = logits[0];
    for (int j = 1; j < 10; ++j) mx = fmaxf(mx, logits[j]);
    float se = 0.f;
    for (int j = 0; j < 10; ++j) se += expf(logits[j] - mx);
    const float lse = mx + logf(se);
    for (int j = 0; j < 10; ++j) out[(size_t)b * 10 + j] = logits[j] - lse;
  }
}

}  // namespace

extern "C" void kernel_launch(void* const* d_in, const int* in_sizes, int n_in,
                              void* d_out, int out_size, void* d_ws, size_t ws_size,
                              hipStream_t stream) {
  const float* x     = (const float*)d_in[0];
  const float* h0    = (const float*)d_in[1];
  const float* c0    = (const float*)d_in[2];
  const float* W1    = (const float*)d_in[3];
  const float* b1    = (const float*)d_in[4];
  const float* Wih_l = (const float*)d_in[5];
  const float* Whh_l = (const float*)d_in[6];
  const float* bih_l = (const float*)d_in[7];
  const float* bhh_l = (const float*)d_in[8];
  const float* Wih_r = (const float*)d_in[9];
  const float* Whh_r = (const float*)d_in[10];
  const float* bih_r = (const float*)d_in[11];
  const float* bhh_r = (const float*)d_in[12];
  const float* Wih_d = (const float*)d_in[13];
  const float* Whh_d = (const float*)d_in[14];
  const float* bih_d = (const float*)d_in[15];
  const float* bhh_d = (const float*)d_in[16];
  const float* W3    = (const float*)d_in[17];
  const float* b3    = (const float*)d_in[18];
  float* out = (float*)d_out;

  char* p = (char*)d_ws;
  auto take = [&](size_t bytes) {
    char* r = p;
    p += (bytes + 255) & ~(size_t)255;
    return r;
  };
  bf16_t* xb    = (bf16_t*)take((size_t)kB * kIN * 2);   // later reused as featT
  bf16_t* w1b   = (bf16_t*)take((size_t)kFS * kIN * 2);  // later reused as hbuf (2 slots)
  bf16_t* feat  = (bf16_t*)take((size_t)kB * kFS * 2);
  bf16_t* wcat  = (bf16_t*)take((size_t)3 * kNG * kKC * 2);
  float*  biasc = (float*)take((size_t)3 * kNG * 4);
  float*  cbuf  = (float*)take((size_t)4 * kB * kH * 4);
  bf16_t* featT = xb;   // safe: gemm_feat (reads xb) precedes transpose (writes featT)
  bf16_t* hbuf  = w1b;  // safe: gemm_feat (reads w1b) precedes pack_hc
  const size_t HSZ = (size_t)4 * kB * kH;

  f2b4_kernel<<<(kB * kIN / 4) / 256, 256, 0, stream>>>(x, xb, kB * kIN / 4);
  f2b4_kernel<<<(kFS * kIN / 4) / 256, 256, 0, stream>>>(W1, w1b, kFS * kIN / 4);
  gemm_feat_kernel<<<dim3(1024), 256, 0, stream>>>(xb, w1b, b1, feat);
  transpose64_kernel<<<kB, 256, 0, stream>>>(feat, featT);
  pack_wcat_kernel<<<(3 * kNG * kKC + 255) / 256, 256, 0, stream>>>(
      Wih_l, Whh_l, Wih_r, Whh_r, Wih_d, Whh_d, wcat);
  pack_bias_kernel<<<(3 * kNG + 255) / 256, 256, 0, stream>>>(
      bih_l, bhh_l, bih_r, bhh_r, bih_d, bhh_d, biasc);
  pack_hc_kernel<<<(int)(HSZ / 256), 256, 0, stream>>>(h0, c0, hbuf, cbuf, (int)HSZ);

  for (int s = 0; s < 64; ++s) {
    lstm_step_kernel<<<dim3(2048), 256, 0, stream>>>(
        feat, featT, wcat, biasc,
        hbuf + (size_t)(s & 1) * HSZ, hbuf + (size_t)((s + 1) & 1) * HSZ, cbuf, s);
  }
  head_kernel<<<kB, 256, 0, stream>>>(hbuf, W3, b3, out);
}

// Round 5
// 4150.666 us; speedup vs baseline: 1.0995x; 1.0560x over previous
//
#include <hip/hip_runtime.h>
#include <cstddef>
#include <cstdint>

namespace {

constexpr int kB  = 4096;   // batch
constexpr int kIN = 4096;
constexpr int kFS = 4096;
constexpr int kS  = 64;
constexpr int kH  = 512;
constexpr int kNG = 2048;   // 4*H
constexpr int kKC = 576;    // 64 (input slice) + 512 (hidden)

typedef __bf16 bf16_t;
typedef __bf16 bfrag  __attribute__((ext_vector_type(8)));
typedef __bf16 bf16v4 __attribute__((ext_vector_type(4)));
typedef float  f32x4  __attribute__((ext_vector_type(4)));

__device__ __forceinline__ void gload16(const void* g, void* l) {
  __builtin_amdgcn_global_load_lds(
      (const __attribute__((address_space(1))) void*)g,
      (__attribute__((address_space(3))) void*)l, 16, 0, 0);
}

__device__ __forceinline__ float sigf(float x) { return 1.0f / (1.0f + __expf(-x)); }
__device__ __forceinline__ float tanh_fast(float x) {
  float e = __expf(2.0f * x);
  return 1.0f - 2.0f / (e + 1.0f);
}

__device__ __forceinline__ f32x4 mfma16(bfrag a, bfrag b, f32x4 c) {
  return __builtin_amdgcn_mfma_f32_16x16x32_bf16(a, b, c, 0, 0, 0);
}

__device__ __forceinline__ void vwait(const int n) {
  if (n == 6)      asm volatile("s_waitcnt vmcnt(6)" ::: "memory");
  else if (n == 4) asm volatile("s_waitcnt vmcnt(4)" ::: "memory");
  else             asm volatile("s_waitcnt vmcnt(0)" ::: "memory");
  __builtin_amdgcn_sched_barrier(0);
}

// ---------------- pack kernels (unchanged) ----------------

__global__ __launch_bounds__(256) void f2b4_kernel(const float* __restrict__ in,
                                                   bf16_t* __restrict__ out, int n4) {
  int i = blockIdx.x * 256 + threadIdx.x;
  if (i >= n4) return;
  float4 v = reinterpret_cast<const float4*>(in)[i];
  bf16v4 o = {(bf16_t)v.x, (bf16_t)v.y, (bf16_t)v.z, (bf16_t)v.w};
  *reinterpret_cast<bf16v4*>(out + (size_t)i * 4) = o;
}

__global__ __launch_bounds__(256) void pack_wcat_kernel(
    const float* __restrict__ Wih_l, const float* __restrict__ Whh_l,
    const float* __restrict__ Wih_r, const float* __restrict__ Whh_r,
    const float* __restrict__ Wih_d, const float* __restrict__ Whh_d,
    bf16_t* __restrict__ wcat) {
  int idx = blockIdx.x * 256 + threadIdx.x;
  if (idx >= 3 * kNG * kKC) return;
  int m = idx / (kNG * kKC);
  int rem = idx - m * (kNG * kKC);
  int rr = rem / kKC;
  int k  = rem - rr * kKC;
  int u = rr >> 2, g = rr & 3;
  int orow = g * kH + u;
  const float* Wih = (m == 0) ? Wih_l : (m == 1) ? Wih_r : Wih_d;
  const float* Whh = (m == 0) ? Whh_l : (m == 1) ? Whh_r : Whh_d;
  float v = (k < 64) ? Wih[(size_t)orow * 64 + k] : Whh[(size_t)orow * 512 + (k - 64)];
  wcat[idx] = (bf16_t)v;
}

__global__ __launch_bounds__(256) void pack_bias_kernel(
    const float* __restrict__ bih_l, const float* __restrict__ bhh_l,
    const float* __restrict__ bih_r, const float* __restrict__ bhh_r,
    const float* __restrict__ bih_d, const float* __restrict__ bhh_d,
    float* __restrict__ biasc) {
  int idx = blockIdx.x * 256 + threadIdx.x;
  if (idx >= 3 * kNG) return;
  int m = idx / kNG;
  int rr = idx - m * kNG;
  int u = rr >> 2, g = rr & 3;
  int orow = g * kH + u;
  const float* bi = (m == 0) ? bih_l : (m == 1) ? bih_r : bih_d;
  const float* bh = (m == 0) ? bhh_l : (m == 1) ? bhh_r : bhh_d;
  biasc[idx] = bi[orow] + bh[orow];
}

__global__ __launch_bounds__(256) void pack_hc_kernel(const float* __restrict__ h0,
                                                      const float* __restrict__ c0,
                                                      bf16_t* __restrict__ hbuf0,
                                                      float* __restrict__ cbuf, int n) {
  int i = blockIdx.x * 256 + threadIdx.x;
  if (i >= n) return;
  hbuf0[i] = (bf16_t)h0[i];
  cbuf[i]  = c0[i];
}

__global__ __launch_bounds__(256) void transpose64_kernel(const bf16_t* __restrict__ feat,
                                                          bf16_t* __restrict__ featT) {
  __shared__ bf16_t tile[64][65];
  const int b = blockIdx.x;
  const bf16_t* src = feat + (size_t)b * kFS;
  bf16_t* dst = featT + (size_t)b * kFS;
  for (int i = threadIdx.x; i < 4096; i += 256) tile[i >> 6][i & 63] = src[i];
  __syncthreads();
  for (int i = threadIdx.x; i < 4096; i += 256) dst[i] = tile[i & 63][i >> 6];
}

// ---------------- feat GEMM (R4 version, unchanged) ----------------

__global__ __launch_bounds__(256, 4) void gemm_feat_kernel(
    const bf16_t* __restrict__ X, const bf16_t* __restrict__ W,
    const float* __restrict__ b1, bf16_t* __restrict__ feat) {
  __shared__ bf16_t As[128 * 32];
  __shared__ bf16_t Bs[128 * 32];
  const int t = threadIdx.x;
  const int bid = blockIdx.x;
  const int widx = (bid & 7) * 128 + (bid >> 3);
  const int bm = widx & 31, bn = widx >> 5;
  const int w = t >> 6, l = t & 63;
  const int wm = (w >> 1) * 64, wn = (w & 1) * 64;
  const int sr = t >> 2;
  const int skS = ((t & 3) ^ ((t >> 3) & 3)) * 8;
  const int lr = l & 15;
  const int lkS = ((l >> 4) ^ ((l >> 1) & 3)) * 8;
  const int lrow4 = (l >> 4) * 4;

  f32x4 acc[4][4];
#pragma unroll
  for (int i = 0; i < 4; ++i)
#pragma unroll
    for (int j = 0; j < 4; ++j) acc[i][j] = (f32x4){0.f, 0.f, 0.f, 0.f};

  const bf16_t* ga = X + (size_t)(bm * 128 + sr) * kIN + skS;
  const bf16_t* gb = W + (size_t)(bn * 128 + sr) * kIN + skS;
  bf16_t* lA = As + w * 512;
  bf16_t* lB = Bs + w * 512;

  for (int kt = 0; kt < kIN / 32; ++kt) {
    gload16(ga, lA);
    gload16(ga + (size_t)64 * kIN, lA + 2048);
    gload16(gb, lB);
    gload16(gb + (size_t)64 * kIN, lB + 2048);
    ga += 32; gb += 32;
    __syncthreads();
    bfrag a[4], b[4];
#pragma unroll
    for (int mi = 0; mi < 4; ++mi)
      a[mi] = *reinterpret_cast<const bfrag*>(&As[(wm + mi * 16 + lr) * 32 + lkS]);
#pragma unroll
    for (int ni = 0; ni < 4; ++ni)
      b[ni] = *reinterpret_cast<const bfrag*>(&Bs[(wn + ni * 16 + lr) * 32 + lkS]);
#pragma unroll
    for (int mi = 0; mi < 4; ++mi)
#pragma unroll
      for (int ni = 0; ni < 4; ++ni)
        acc[mi][ni] = __builtin_amdgcn_mfma_f32_16x16x32_bf16(a[mi], b[ni], acc[mi][ni], 0, 0, 0);
    __syncthreads();
  }

#pragma unroll
  for (int ni = 0; ni < 4; ++ni) {
    const int col = bn * 128 + wn + ni * 16 + lr;
    const float bb = b1[col];
#pragma unroll
    for (int mi = 0; mi < 4; ++mi) {
#pragma unroll
      for (int r = 0; r < 4; ++r) {
        const int row = bm * 128 + wm + mi * 16 + lrow4 + r;
        float v = acc[mi][ni][r] + bb;
        feat[(size_t)row * kFS + col] = (bf16_t)fmaxf(v, 0.0f);
      }
    }
  }
}

// ---------------- 256x256 8-wave 4-phase-per-K-tile step kernel ----------------
// LDS (dynamic, 128 KB): slot p (p = K-tile & 1): A[256][64] bf16 + B[256][64] bf16.
// T2 swizzle: LDS[row][slot16B s] = global[row][s ^ (row&7)], via linear
// global_load_lds dest + pre-swizzled per-lane global source (rule #21).
// Region rotation (16 KB regions A-mh0/A-mh1/B-nh0/B-nh1), 1-phase-lag staging,
// vmcnt(6) per phase end; prologue vmcnt(4); tail drains 4 -> 0 (derived; see R4 notes).

template <class F1, class F2, class F3, class F4>
__device__ __forceinline__ void run_tile(
    const bf16_t* __restrict__ As_, const bf16_t* __restrict__ Bs_,
    f32x4 (&acc)[8][4], const int wr, const int wc, const int lr, const int lq,
    F1&& st1, F2&& st2, F3&& st3, F4&& st4,
    const int v1, const int v2, const int v3, const int v4) {
  bfrag a[8], b[8];
  const int sx = lr & 7;

  // ---- phase 1: read A-mh0 + B-nh0; stage; quad (0,0) ----
#pragma unroll
  for (int mm = 0; mm < 4; ++mm)
#pragma unroll
    for (int kk = 0; kk < 2; ++kk)
      a[mm * 2 + kk] = *reinterpret_cast<const bfrag*>(
          As_ + (wr * 128 + mm * 16 + lr) * 64 + (((kk * 4 + lq) ^ sx) * 8));
#pragma unroll
  for (int nn = 0; nn < 2; ++nn)
#pragma unroll
    for (int kk = 0; kk < 2; ++kk)
      b[nn * 2 + kk] = *reinterpret_cast<const bfrag*>(
          Bs_ + (wc * 64 + nn * 16 + lr) * 64 + (((kk * 4 + lq) ^ sx) * 8));
  st1();
  __builtin_amdgcn_s_barrier();
  asm volatile("s_waitcnt lgkmcnt(0)" ::: "memory");
  __builtin_amdgcn_sched_barrier(0);
  __builtin_amdgcn_s_setprio(1);
#pragma unroll
  for (int kk = 0; kk < 2; ++kk)
#pragma unroll
    for (int mm = 0; mm < 4; ++mm)
#pragma unroll
      for (int nn = 0; nn < 2; ++nn)
        acc[mm][nn] = mfma16(a[mm * 2 + kk], b[nn * 2 + kk], acc[mm][nn]);
  __builtin_amdgcn_s_setprio(0);
  __builtin_amdgcn_sched_barrier(0);
  vwait(v1);
  __builtin_amdgcn_s_barrier();

  // ---- phase 2: read B-nh1; stage; quad (0,1) ----
#pragma unroll
  for (int nn = 0; nn < 2; ++nn)
#pragma unroll
    for (int kk = 0; kk < 2; ++kk)
      b[4 + nn * 2 + kk] = *reinterpret_cast<const bfrag*>(
          Bs_ + (wc * 64 + 32 + nn * 16 + lr) * 64 + (((kk * 4 + lq) ^ sx) * 8));
  st2();
  __builtin_amdgcn_s_barrier();
  asm volatile("s_waitcnt lgkmcnt(0)" ::: "memory");
  __builtin_amdgcn_sched_barrier(0);
  __builtin_amdgcn_s_setprio(1);
#pragma unroll
  for (int kk = 0; kk < 2; ++kk)
#pragma unroll
    for (int mm = 0; mm < 4; ++mm)
#pragma unroll
      for (int nn = 0; nn < 2; ++nn)
        acc[mm][2 + nn] = mfma16(a[mm * 2 + kk], b[4 + nn * 2 + kk], acc[mm][2 + nn]);
  __builtin_amdgcn_s_setprio(0);
  __builtin_amdgcn_sched_barrier(0);
  vwait(v2);
  __builtin_amdgcn_s_barrier();

  // ---- phase 3: read A-mh1; stage; quad (1,0) ----
#pragma unroll
  for (int mm = 0; mm < 4; ++mm)
#pragma unroll
    for (int kk = 0; kk < 2; ++kk)
      a[mm * 2 + kk] = *reinterpret_cast<const bfrag*>(
          As_ + (wr * 128 + 64 + mm * 16 + lr) * 64 + (((kk * 4 + lq) ^ sx) * 8));
  st3();
  __builtin_amdgcn_s_barrier();
  asm volatile("s_waitcnt lgkmcnt(0)" ::: "memory");
  __builtin_amdgcn_sched_barrier(0);
  __builtin_amdgcn_s_setprio(1);
#pragma unroll
  for (int kk = 0; kk < 2; ++kk)
#pragma unroll
    for (int mm = 0; mm < 4; ++mm)
#pragma unroll
      for (int nn = 0; nn < 2; ++nn)
        acc[4 + mm][nn] = mfma16(a[mm * 2 + kk], b[nn * 2 + kk], acc[4 + mm][nn]);
  __builtin_amdgcn_s_setprio(0);
  __builtin_amdgcn_sched_barrier(0);
  vwait(v3);
  __builtin_amdgcn_s_barrier();

  // ---- phase 4: stage; quad (1,1) ----
  st4();
  __builtin_amdgcn_s_barrier();
  asm volatile("s_waitcnt lgkmcnt(0)" ::: "memory");
  __builtin_amdgcn_sched_barrier(0);
  __builtin_amdgcn_s_setprio(1);
#pragma unroll
  for (int kk = 0; kk < 2; ++kk)
#pragma unroll
    for (int mm = 0; mm < 4; ++mm)
#pragma unroll
      for (int nn = 0; nn < 2; ++nn)
        acc[4 + mm][2 + nn] = mfma16(a[mm * 2 + kk], b[4 + nn * 2 + kk], acc[4 + mm][2 + nn]);
  __builtin_amdgcn_s_setprio(0);
  __builtin_amdgcn_sched_barrier(0);
  vwait(v4);
  __builtin_amdgcn_s_barrier();
}

__global__ __launch_bounds__(512, 2) void lstm_step256_kernel(
    const bf16_t* __restrict__ feat, const bf16_t* __restrict__ featT,
    const bf16_t* __restrict__ wcat, const float* __restrict__ biasc,
    const bf16_t* __restrict__ hin, bf16_t* __restrict__ hout,
    float* __restrict__ cbuf, int s) {
  extern __shared__ __align__(16) char smem[];
  bf16_t* Ab[2] = {(bf16_t*)smem, (bf16_t*)(smem + 65536)};
  bf16_t* Bb[2] = {(bf16_t*)(smem + 32768), (bf16_t*)(smem + 98304)};

  const int t = threadIdx.x;
  const int l = t & 63, w = t >> 6;
  const int wr = w >> 2, wc = w & 3;     // 2M x 4N wave grid; wave tile 128x64
  const int lr = l & 15, lq = l >> 4;
  const int srow = l >> 3;               // staging: row within 8-row group
  const int sslot = (l & 7) ^ srow;      // pre-swizzled global 16B-slot

  // grid 512 = 4 cell x 16 bm x 8 bn; XCD swizzle (bijective, 512%8==0)
  const int bid = blockIdx.x;
  const int widx = (bid & 7) * 64 + (bid >> 3);
  const int cell = widx >> 7;
  const int rwk = widx & 127;
  const int bm = rwk >> 3, bn = rwk & 7;

  const bf16_t* xsrc = (cell < 2) ? feat : featT;
  const int off = ((cell & 1) ? (63 - s) : s) * 64;
  const int mat = (cell < 2) ? cell : 2;
  const bf16_t* Wm = wcat + (size_t)mat * kNG * kKC;
  const bf16_t* hc = hin + (size_t)cell * kB * kH;

  auto stage_A = [&](int kt, bf16_t* dstA, int ra) {
#pragma unroll
    for (int j = 0; j < 2; ++j) {
      const int row0 = ra * 64 + w * 8 + j * 128;   // wave-uniform
      bf16_t* dst = dstA + row0 * 64;
      const bf16_t* src = (kt == 0)
          ? xsrc + (size_t)(bm * 256 + row0 + srow) * kFS + off + sslot * 8
          : hc + (size_t)(bm * 256 + row0 + srow) * kH + (kt - 1) * 64 + sslot * 8;
      gload16(src, dst);
    }
  };
  auto stage_B = [&](int kt, bf16_t* dstB, int rb) {
#pragma unroll
    for (int j = 0; j < 2; ++j) {
      const int row0 = (w >> 2) * 64 + (w & 3) * 8 + rb * 32 + j * 128;
      bf16_t* dst = dstB + row0 * 64;
      const bf16_t* src =
          Wm + (size_t)(bn * 256 + row0 + srow) * kKC + kt * 64 + sslot * 8;
      gload16(src, dst);
    }
  };

  f32x4 acc[8][4];
#pragma unroll
  for (int i = 0; i < 8; ++i)
#pragma unroll
    for (int j = 0; j < 4; ++j) acc[i][j] = (f32x4){0.f, 0.f, 0.f, 0.f};

  // prologue: tile0 full + tile1 {A0,B0}; wait all but last 2 regions
  stage_A(0, Ab[0], 0); stage_B(0, Bb[0], 0);
  stage_A(0, Ab[0], 1); stage_B(0, Bb[0], 1);
  stage_A(1, Ab[1], 0); stage_B(1, Bb[1], 0);
  vwait(4);
  __builtin_amdgcn_s_barrier();

  // tile 0 (x-slice), slot 0
  run_tile(Ab[0], Bb[0], acc, wr, wc, lr, lq,
           [&] { stage_A(1, Ab[1], 1); }, [&] { stage_B(1, Bb[1], 1); },
           [&] { stage_A(2, Ab[0], 0); }, [&] { stage_B(2, Bb[0], 0); },
           6, 6, 6, 6);

  // tiles 1..6 (h), pairs {S,S+1}, S = 1,3,5
  for (int S = 1; S <= 5; S += 2) {
    run_tile(Ab[1], Bb[1], acc, wr, wc, lr, lq,
             [&] { stage_A(S + 1, Ab[0], 1); }, [&] { stage_B(S + 1, Bb[0], 1); },
             [&] { stage_A(S + 2, Ab[1], 0); }, [&] { stage_B(S + 2, Bb[1], 0); },
             6, 6, 6, 6);
    run_tile(Ab[0], Bb[0], acc, wr, wc, lr, lq,
             [&] { stage_A(S + 2, Ab[1], 1); }, [&] { stage_B(S + 2, Bb[1], 1); },
             [&] { stage_A(S + 3, Ab[0], 0); }, [&] { stage_B(S + 3, Bb[0], 0); },
             6, 6, 6, 6);
  }
  // tile 7 (slot1): only A1(8)/B1(8) remain to stage; begin drain
  run_tile(Ab[1], Bb[1], acc, wr, wc, lr, lq,
           [&] { stage_A(8, Ab[0], 1); }, [&] { stage_B(8, Bb[0], 1); },
           [&] {}, [&] {}, 6, 6, 6, 4);
  // tile 8 (slot0): no staging; full drain after phase 1
  run_tile(Ab[0], Bb[0], acc, wr, wc, lr, lq,
           [&] {}, [&] {}, [&] {}, [&] {}, 0, 0, 0, 0);

  // ---- epilogue: per-wave private gate fusion (no barriers needed) ----
  // Wave's 64 N-cols = 16 complete units (4 gates each). Gs[32][68] f32 per wave.
  float* Gw = (float*)smem + w * 2176;   // 8704 B per wave, 69632 total < 128 KB
  const float* biasn = biasc + mat * kNG + bn * 256 + wc * 64;
  float bb[4];
#pragma unroll
  for (int n = 0; n < 4; ++n) bb[n] = biasn[n * 16 + lr];
  const int rowg0 = bm * 256 + wr * 128;
  const int unit = bn * 64 + wc * 16 + lr;
#pragma unroll
  for (int ch = 0; ch < 4; ++ch) {
#pragma unroll
    for (int mm = 0; mm < 2; ++mm) {
      const int m = ch * 2 + mm;
#pragma unroll
      for (int n = 0; n < 4; ++n)
#pragma unroll
        for (int j = 0; j < 4; ++j)
          Gw[(mm * 16 + lq * 4 + j) * 68 + n * 16 + lr] = acc[m][n][j] + bb[n];
    }
#pragma unroll
    for (int rr = 0; rr < 8; ++rr) {
      const int row = rr * 4 + lq;
      const float4 g4 = *reinterpret_cast<const float4*>(&Gw[row * 68 + lr * 4]);
      const float iv = sigf(g4.x);
      const float fv = sigf(g4.y);
      const float gv = tanh_fast(g4.z);
      const float ov = sigf(g4.w);
      const int grow = rowg0 + ch * 32 + row;
      const size_t cidx = ((size_t)cell * kB + grow) * kH + unit;
      const float cn = fv * cbuf[cidx] + iv * gv;
      cbuf[cidx] = cn;
      hout[cidx] = (bf16_t)(ov * tanh_fast(cn));
    }
  }
}

// ---------------- head ----------------

__global__ __launch_bounds__(256) void head_kernel(const bf16_t* __restrict__ hfin,
                                                   const float* __restrict__ W3,
                                                   const float* __restrict__ b3,
                                                   float* __restrict__ out) {
  const int b = blockIdx.x, t = threadIdx.x;
  float acc[10];
#pragma unroll
  for (int j = 0; j < 10; ++j) acc[j] = 0.f;
  for (int k = t; k < 2048; k += 256) {
    const int cell = k >> 9, u = k & 511;
    const float hv = (float)hfin[((size_t)cell * kB + b) * kH + u];
#pragma unroll
    for (int j = 0; j < 10; ++j) acc[j] += hv * W3[j * 2048 + k];
  }
  __shared__ float red[256];
  __shared__ float logits[10];
  for (int j = 0; j < 10; ++j) {
    red[t] = acc[j];
    __syncthreads();
    for (int o2 = 128; o2 > 0; o2 >>= 1) {
      if (t < o2) red[t] += red[t + o2];
      __syncthreads();
    }
    if (t == 0) logits[j] = red[0] + b3[j];
    __syncthreads();
  }
  if (t == 0) {
    float mx = logits[0];
    for (int j = 1; j < 10; ++j) mx = fmaxf(mx, logits[j]);
    float se = 0.f;
    for (int j = 0; j < 10; ++j) se += expf(logits[j] - mx);
    const float lse = mx + logf(se);
    for (int j = 0; j < 10; ++j) out[(size_t)b * 10 + j] = logits[j] - lse;
  }
}

}  // namespace

extern "C" void kernel_launch(void* const* d_in, const int* in_sizes, int n_in,
                              void* d_out, int out_size, void* d_ws, size_t ws_size,
                              hipStream_t stream) {
  const float* x     = (const float*)d_in[0];
  const float* h0    = (const float*)d_in[1];
  const float* c0    = (const float*)d_in[2];
  const float* W1    = (const float*)d_in[3];
  const float* b1    = (const float*)d_in[4];
  const float* Wih_l = (const float*)d_in[5];
  const float* Whh_l = (const float*)d_in[6];
  const float* bih_l = (const float*)d_in[7];
  const float* bhh_l = (const float*)d_in[8];
  const float* Wih_r = (const float*)d_in[9];
  const float* Whh_r = (const float*)d_in[10];
  const float* bih_r = (const float*)d_in[11];
  const float* bhh_r = (const float*)d_in[12];
  const float* Wih_d = (const float*)d_in[13];
  const float* Whh_d = (const float*)d_in[14];
  const float* bih_d = (const float*)d_in[15];
  const float* bhh_d = (const float*)d_in[16];
  const float* W3    = (const float*)d_in[17];
  const float* b3    = (const float*)d_in[18];
  float* out = (float*)d_out;

  char* p = (char*)d_ws;
  auto take = [&](size_t bytes) {
    char* r = p;
    p += (bytes + 255) & ~(size_t)255;
    return r;
  };
  bf16_t* xb    = (bf16_t*)take((size_t)kB * kIN * 2);   // later reused as featT
  bf16_t* w1b   = (bf16_t*)take((size_t)kFS * kIN * 2);  // later reused as hbuf (2 slots)
  bf16_t* feat  = (bf16_t*)take((size_t)kB * kFS * 2);
  bf16_t* wcat  = (bf16_t*)take((size_t)3 * kNG * kKC * 2);
  float*  biasc = (float*)take((size_t)3 * kNG * 4);
  float*  cbuf  = (float*)take((size_t)4 * kB * kH * 4);
  bf16_t* featT = xb;   // safe: gemm_feat (reads xb) precedes transpose (writes featT)
  bf16_t* hbuf  = w1b;  // safe: gemm_feat (reads w1b) precedes pack_hc
  const size_t HSZ = (size_t)4 * kB * kH;

  // allow 128 KB dynamic LDS for the step kernel (idempotent; not a stream op)
  (void)hipFuncSetAttribute(reinterpret_cast<const void*>(&lstm_step256_kernel),
                            hipFuncAttributeMaxDynamicSharedMemorySize, 131072);

  f2b4_kernel<<<(kB * kIN / 4) / 256, 256, 0, stream>>>(x, xb, kB * kIN / 4);
  f2b4_kernel<<<(kFS * kIN / 4) / 256, 256, 0, stream>>>(W1, w1b, kFS * kIN / 4);
  gemm_feat_kernel<<<dim3(1024), 256, 0, stream>>>(xb, w1b, b1, feat);
  transpose64_kernel<<<kB, 256, 0, stream>>>(feat, featT);
  pack_wcat_kernel<<<(3 * kNG * kKC + 255) / 256, 256, 0, stream>>>(
      Wih_l, Whh_l, Wih_r, Whh_r, Wih_d, Whh_d, wcat);
  pack_bias_kernel<<<(3 * kNG + 255) / 256, 256, 0, stream>>>(
      bih_l, bhh_l, bih_r, bhh_r, bih_d, bhh_d, biasc);
  pack_hc_kernel<<<(int)(HSZ / 256), 256, 0, stream>>>(h0, c0, hbuf, cbuf, (int)HSZ);

  for (int s = 0; s < 64; ++s) {
    lstm_step256_kernel<<<dim3(512), 512, 131072, stream>>>(
        feat, featT, wcat, biasc,
        hbuf + (size_t)(s & 1) * HSZ, hbuf + (size_t)((s + 1) & 1) * HSZ, cbuf, s);
  }
  head_kernel<<<kB, 256, 0, stream>>>(hbuf, W3, b3, out);
}